// Round 1
// baseline (539.686 us; speedup 1.0000x reference)
//
#include <hip/hip_runtime.h>

#define BATCH 32
#define TT 8
#define VOCAB 2048
#define EMB 256
#define NG 8192        // 4*VOCAB
#define LAT 128
#define KC 16          // k-chunks for Wh GEMM
#define KCHUNK 128     // VOCAB/KC

// ws layout (float offsets)
#define XWI_OFF 0
#define XWI_SZ  (7*BATCH*NG)        // 1,835,008 floats
#define P_OFF   (XWI_OFF + XWI_SZ)
#define P_SZ    (KC*BATCH*NG)       // 4,194,304 floats
#define H_OFF   (P_OFF + P_SZ)
#define H_SZ    (BATCH*VOCAB)
#define C_OFF   (H_OFF + H_SZ)

__device__ __forceinline__ float sigmoidf_(float x){ return 1.f/(1.f+__expf(-x)); }
__device__ __forceinline__ float tanhf_(float x){
  x = fminf(fmaxf(x, -10.f), 10.f);
  float e = __expf(2.f*x);
  return (e-1.f)/(e+1.f);
}

__global__ void k_init(float* __restrict__ h, float* __restrict__ c, float* __restrict__ out){
  int i = blockIdx.x*256 + threadIdx.x;
  if (i < BATCH*VOCAB){ h[i] = 0.f; c[i] = 0.f; }
  if (i < BATCH*LAT){
    int b = i >> 7, l = i & (LAT-1);
    out[(b*TT + 0)*LAT + l] = 0.f;   // t=0 output is exactly zero (rng=0)
  }
}

// xWi[t][b][n] = E[tok[b][t]] . Wi[:,n] + bias[n], t = 0..6
__global__ void k_xwi(const int* __restrict__ tok, const float* __restrict__ E,
                      const float* __restrict__ Wi, const float* __restrict__ bias,
                      float* __restrict__ xWi){
  const int t = blockIdx.y;                       // 0..6
  const int n = blockIdx.x*256 + threadIdx.x;     // 0..8191
  __shared__ float xs[BATCH][EMB+4];              // row stride 260 floats (16B-aligned)
  for (int i = threadIdx.x; i < BATCH*EMB; i += 256){
    int b = i >> 8, k = i & (EMB-1);
    xs[b][k] = E[tok[b*TT + t]*EMB + k];
  }
  __syncthreads();
  float acc[BATCH];
  #pragma unroll
  for (int b=0;b<BATCH;b++) acc[b] = 0.f;
  for (int k=0;k<EMB;k+=4){
    float w0 = Wi[(k+0)*NG+n], w1 = Wi[(k+1)*NG+n];
    float w2 = Wi[(k+2)*NG+n], w3 = Wi[(k+3)*NG+n];
    #pragma unroll
    for (int b=0;b<BATCH;b++){
      float4 x4 = *(const float4*)&xs[b][k];      // LDS broadcast, 16B-aligned
      acc[b] = fmaf(x4.x,w0,fmaf(x4.y,w1,fmaf(x4.z,w2,fmaf(x4.w,w3,acc[b]))));
    }
  }
  float bb = bias[n];
  #pragma unroll
  for (int b=0;b<BATCH;b++)
    xWi[(size_t)(t*BATCH + b)*NG + n] = acc[b] + bb;
}

// P[kc][b][n] = sum_{k in chunk kc} h[b][k] * Wh[k][n]
__global__ void k_whgemm(const float* __restrict__ h, const float* __restrict__ Wh,
                         float* __restrict__ P){
  const int n  = blockIdx.x*256 + threadIdx.x;
  const int kc = blockIdx.y;
  const int k0 = kc*KCHUNK;
  __shared__ float hs[BATCH][KCHUNK+4];           // row stride 132 floats (16B-aligned)
  for (int i = threadIdx.x; i < BATCH*KCHUNK; i += 256){
    int b = i >> 7, k = i & (KCHUNK-1);
    hs[b][k] = h[b*VOCAB + k0 + k];
  }
  __syncthreads();
  float acc[BATCH];
  #pragma unroll
  for (int b=0;b<BATCH;b++) acc[b] = 0.f;
  for (int k=0;k<KCHUNK;k+=4){
    const float* wp = Wh + (size_t)(k0+k)*NG + n;
    float w0 = wp[0], w1 = wp[NG], w2 = wp[2*NG], w3 = wp[3*NG];
    #pragma unroll
    for (int b=0;b<BATCH;b++){
      float4 h4 = *(const float4*)&hs[b][k];
      acc[b] = fmaf(h4.x,w0,fmaf(h4.y,w1,fmaf(h4.z,w2,fmaf(h4.w,w3,acc[b]))));
    }
  }
  #pragma unroll
  for (int b=0;b<BATCH;b++)
    P[(size_t)(kc*BATCH + b)*NG + n] = acc[b];
}

// Reduce partials -> gates -> LSTM cell update (masked) -> softmax stats -> out[b][t][:]
__global__ void k_cell(const int* __restrict__ tok, const float* __restrict__ xWi,
                       const float* __restrict__ P, float* __restrict__ h,
                       float* __restrict__ c, float* __restrict__ out, int t){
  const int b = blockIdx.x;
  const int tid = threadIdx.x;
  const int lane = tid & 63, wid = tid >> 6;
  const int tokPrev = tok[b*TT + (t-1)];
  const int sj = tok[b*TT + t];
  const bool upd = (tokPrev != 0);
  const float* xw = xWi + (size_t)((t-1)*BATCH + b)*NG;

  float hv[8];
  #pragma unroll
  for (int u=0;u<8;u++){
    int j = tid + 256*u;
    float ip = xw[j], fp = xw[j+VOCAB], gp = xw[j+2*VOCAB], op = xw[j+3*VOCAB];
    for (int kc=0;kc<KC;kc++){
      const float* Pp = P + (size_t)(kc*BATCH + b)*NG;
      ip += Pp[j]; fp += Pp[j+VOCAB]; gp += Pp[j+2*VOCAB]; op += Pp[j+3*VOCAB];
    }
    float cold = c[b*VOCAB + j];
    float cn = sigmoidf_(fp)*cold + sigmoidf_(ip)*tanhf_(gp);
    float hn = sigmoidf_(op)*tanhf_(cn);
    float hf, cf;
    if (upd){ hf = hn; cf = cn; }
    else    { hf = h[b*VOCAB + j]; cf = cold; }
    h[b*VOCAB + j] = hf;
    c[b*VOCAB + j] = cf;
    hv[u] = hf;
  }

  __shared__ float redA[4], redB[4];
  __shared__ float esj_sh;
  // max over 2048
  float m = -1e30f;
  #pragma unroll
  for (int u=0;u<8;u++) m = fmaxf(m, hv[u]);
  #pragma unroll
  for (int off=32; off; off>>=1) m = fmaxf(m, __shfl_down(m, off));
  if (lane==0) redA[wid] = m;
  __syncthreads();
  m = fmaxf(fmaxf(redA[0],redA[1]), fmaxf(redA[2],redA[3]));
  __syncthreads();
  // Z = sum exp, S = prefix sum below sj, esj = exp at sj
  float z = 0.f, s = 0.f;
  #pragma unroll
  for (int u=0;u<8;u++){
    int j = tid + 256*u;
    float e = __expf(hv[u]-m);
    z += e;
    if (j < sj)  s += e;
    if (j == sj) esj_sh = e;
  }
  #pragma unroll
  for (int off=32; off; off>>=1){ z += __shfl_down(z, off); s += __shfl_down(s, off); }
  if (lane==0){ redA[wid] = z; redB[wid] = s; }
  __syncthreads();
  float Z = redA[0]+redA[1]+redA[2]+redA[3];
  float S = redB[0]+redB[1]+redB[2]+redB[3];
  float v = (3.f*S + 1.5f*esj_sh)/Z;
  if (tid < LAT) out[(size_t)(b*TT + t)*LAT + tid] = v;
}

extern "C" void kernel_launch(void* const* d_in, const int* in_sizes, int n_in,
                              void* d_out, int out_size, void* d_ws, size_t ws_size,
                              hipStream_t stream){
  const int*   tok  = (const int*)d_in[0];
  const float* E    = (const float*)d_in[1];
  const float* Wi   = (const float*)d_in[2];
  const float* Wh   = (const float*)d_in[3];
  const float* bias = (const float*)d_in[4];
  float* out = (float*)d_out;
  float* ws  = (float*)d_ws;
  float* xWi = ws + XWI_OFF;
  float* P   = ws + P_OFF;
  float* h   = ws + H_OFF;
  float* c   = ws + C_OFF;

  k_init<<<256, 256, 0, stream>>>(h, c, out);
  k_xwi<<<dim3(32,7), 256, 0, stream>>>(tok, E, Wi, bias, xWi);
  for (int t = 1; t < TT; t++){
    k_whgemm<<<dim3(32,KC), 256, 0, stream>>>(h, Wh, P);
    k_cell<<<32, 256, 0, stream>>>(tok, xWi, P, h, c, out, t);
  }
}

// Round 2
// 524.004 us; speedup vs baseline: 1.0299x; 1.0299x over previous
//
#include <hip/hip_runtime.h>

#define BATCH 32
#define TT 8
#define VOCAB 2048
#define EMB 256
#define NG 8192          // 4*VOCAB
#define LAT 128
#define KCHUNK 128
#define KC 18            // 2 x-chunks (Wi, K=256) + 16 h-chunks (Wh, K=2048)

// ws layout (float offsets)
#define P_OFF   0
#define P_SZ    (KC*BATCH*NG)      // 4,718,592 floats (~18.9 MB)
#define H_OFF   (P_OFF + P_SZ)
#define H_SZ    (BATCH*VOCAB)
#define C_OFF   (H_OFF + H_SZ)
#define C_SZ    (BATCH*VOCAB)
#define ST_OFF  (C_OFF + C_SZ)
#define ST_SZ   (BATCH*8*2)        // per-(b, jc) partial {Z, S}
#define ESJ_OFF (ST_OFF + ST_SZ)

__device__ __forceinline__ float sigmoidf_(float x){ return 1.f/(1.f+__expf(-x)); }
__device__ __forceinline__ float tanhf_(float x){
  x = fminf(fmaxf(x, -10.f), 10.f);
  float e = __expf(2.f*x);
  return (e-1.f)/(e+1.f);
}

__global__ void k_init(float* __restrict__ h, float* __restrict__ c, float* __restrict__ out){
  int i = blockIdx.x*256 + threadIdx.x;
  if (i < BATCH*VOCAB){ h[i] = 0.f; c[i] = 0.f; }
  if (i < BATCH*LAT){
    int b = i >> 7, l = i & (LAT-1);
    out[(size_t)(b*TT + 0)*LAT + l] = 0.f;   // t=0: rng=0 -> z=0 exactly
  }
}

// Fused [x,h] @ [Wi;Wh] -> P[kc][b][n].  kc<2: x=E[tok[:,t-1]] vs Wi rows;
// kc>=2: h vs Wh rows. Each thread: 4 consecutive n (float4 W loads) x 8 batches.
// Designated block (0,0,0) also finalizes the PREVIOUS step's output (t>=2).
__global__ __launch_bounds__(256) void k_gemm(
    const int* __restrict__ tok, const float* __restrict__ E,
    const float* __restrict__ Wi, const float* __restrict__ Wh,
    const float* __restrict__ h, float* __restrict__ P,
    const float* __restrict__ stats, const float* __restrict__ esj,
    float* __restrict__ out, int t){
  const int tid = threadIdx.x;
  const int nb = blockIdx.x, kc = blockIdx.y, bg = blockIdx.z;

  __shared__ float xs[8][KCHUNK+4];     // row stride 132 floats = 528 B (16B-aligned)
  __shared__ float vsh[BATCH];

  if (nb==0 && kc==0 && bg==0 && t>=2){     // block-uniform branch
    if (tid < BATCH){
      float Z=0.f, S=0.f;
      #pragma unroll
      for (int jc=0;jc<8;jc++){ Z += stats[(tid*8+jc)*2]; S += stats[(tid*8+jc)*2+1]; }
      vsh[tid] = (3.f*S + 1.5f*esj[tid])/Z;
    }
    __syncthreads();
    for (int i=tid; i<BATCH*LAT; i+=256)
      out[(size_t)((i>>7)*TT + (t-1))*LAT + (i&(LAT-1))] = vsh[i>>7];
    __syncthreads();
  }

  const bool xpart = (kc < 2);
  const int row0 = xpart ? kc*KCHUNK : (kc-2)*KCHUNK;
  for (int i=tid; i<8*KCHUNK; i+=256){
    int bi = i>>7, k = i&(KCHUNK-1);
    int b = bg*8 + bi;
    xs[bi][k] = xpart ? E[(size_t)tok[b*TT + (t-1)]*EMB + row0 + k]
                      : h[b*VOCAB + row0 + k];
  }
  __syncthreads();

  const float* __restrict__ W = xpart ? Wi : Wh;
  const int n0 = (nb*256 + tid)*4;
  float4 acc[8];
  #pragma unroll
  for (int bi=0;bi<8;bi++) acc[bi] = make_float4(0.f,0.f,0.f,0.f);

  for (int kq=0; kq<KCHUNK/4; kq++){
    const int k = kq*4;
    const float* wp = W + (size_t)(row0+k)*NG + n0;
    float4 w0 = *(const float4*)(wp);
    float4 w1 = *(const float4*)(wp + NG);
    float4 w2 = *(const float4*)(wp + 2*(size_t)NG);
    float4 w3 = *(const float4*)(wp + 3*(size_t)NG);
    #pragma unroll
    for (int bi=0;bi<8;bi++){
      float4 hv = *(const float4*)&xs[bi][k];
      acc[bi].x = fmaf(hv.x,w0.x,fmaf(hv.y,w1.x,fmaf(hv.z,w2.x,fmaf(hv.w,w3.x,acc[bi].x))));
      acc[bi].y = fmaf(hv.x,w0.y,fmaf(hv.y,w1.y,fmaf(hv.z,w2.y,fmaf(hv.w,w3.y,acc[bi].y))));
      acc[bi].z = fmaf(hv.x,w0.z,fmaf(hv.y,w1.z,fmaf(hv.z,w2.z,fmaf(hv.w,w3.z,acc[bi].z))));
      acc[bi].w = fmaf(hv.x,w0.w,fmaf(hv.y,w1.w,fmaf(hv.z,w2.w,fmaf(hv.w,w3.w,acc[bi].w))));
    }
  }
  #pragma unroll
  for (int bi=0;bi<8;bi++)
    *(float4*)&P[(size_t)(kc*BATCH + bg*8 + bi)*NG + n0] = acc[bi];
}

// Reduce the KC partial slabs -> gates -> masked LSTM cell update -> h,c
// -> per-block partial softmax stats (fixed max: h in (-1,1), exp(h) safe).
__global__ __launch_bounds__(256) void k_cellred(
    const int* __restrict__ tok, const float* __restrict__ bias,
    const float* __restrict__ P, float* __restrict__ h, float* __restrict__ c,
    float* __restrict__ stats, float* __restrict__ esj, int t){
  const int tid = threadIdx.x;
  const int jc = blockIdx.x, b = blockIdx.y;
  const int j = jc*256 + tid;
  const int lane = tid & 63, wid = tid >> 6;

  float ip = bias[j], fp = bias[j+VOCAB], gp = bias[j+2*VOCAB], op = bias[j+3*VOCAB];
  for (int kc=0;kc<KC;kc++){
    const float* Pp = P + (size_t)(kc*BATCH + b)*NG;
    ip += Pp[j]; fp += Pp[j+VOCAB]; gp += Pp[j+2*VOCAB]; op += Pp[j+3*VOCAB];
  }
  float cold = c[b*VOCAB + j];
  float cn = sigmoidf_(fp)*cold + sigmoidf_(ip)*tanhf_(gp);
  float hn = sigmoidf_(op)*tanhf_(cn);
  const bool upd = tok[b*TT + (t-1)] != 0;
  float hf = upd ? hn : h[b*VOCAB + j];
  float cf = upd ? cn : cold;
  h[b*VOCAB + j] = hf;
  c[b*VOCAB + j] = cf;

  const int sj = tok[b*TT + t];
  float e = __expf(hf);
  float z = e, s = (j < sj) ? e : 0.f;
  if (j == sj) esj[b] = e;

  __shared__ float zsh[4], ssh[4];
  #pragma unroll
  for (int off=32; off; off>>=1){ z += __shfl_down(z, off); s += __shfl_down(s, off); }
  if (lane==0){ zsh[wid] = z; ssh[wid] = s; }
  __syncthreads();
  if (tid==0){
    stats[(b*8 + jc)*2 + 0] = zsh[0]+zsh[1]+zsh[2]+zsh[3];
    stats[(b*8 + jc)*2 + 1] = ssh[0]+ssh[1]+ssh[2]+ssh[3];
  }
}

// Final output write for t = TT-1.
__global__ __launch_bounds__(256) void k_out(
    const float* __restrict__ stats, const float* __restrict__ esj,
    float* __restrict__ out, int t){
  const int tid = threadIdx.x;
  __shared__ float vsh[BATCH];
  if (tid < BATCH){
    float Z=0.f, S=0.f;
    #pragma unroll
    for (int jc=0;jc<8;jc++){ Z += stats[(tid*8+jc)*2]; S += stats[(tid*8+jc)*2+1]; }
    vsh[tid] = (3.f*S + 1.5f*esj[tid])/Z;
  }
  __syncthreads();
  for (int i=tid; i<BATCH*LAT; i+=256)
    out[(size_t)((i>>7)*TT + t)*LAT + (i&(LAT-1))] = vsh[i>>7];
}

extern "C" void kernel_launch(void* const* d_in, const int* in_sizes, int n_in,
                              void* d_out, int out_size, void* d_ws, size_t ws_size,
                              hipStream_t stream){
  const int*   tok  = (const int*)d_in[0];
  const float* E    = (const float*)d_in[1];
  const float* Wi   = (const float*)d_in[2];
  const float* Wh   = (const float*)d_in[3];
  const float* bias = (const float*)d_in[4];
  float* out = (float*)d_out;
  float* ws  = (float*)d_ws;
  float* P     = ws + P_OFF;
  float* h     = ws + H_OFF;
  float* c     = ws + C_OFF;
  float* stats = ws + ST_OFF;
  float* esj   = ws + ESJ_OFF;

  k_init<<<256, 256, 0, stream>>>(h, c, out);
  for (int t = 1; t < TT; t++){
    k_gemm<<<dim3(8, KC, 4), 256, 0, stream>>>(tok, E, Wi, Wh, h, P, stats, esj, out, t);
    k_cellred<<<dim3(8, BATCH), 256, 0, stream>>>(tok, bias, P, h, c, stats, esj, t);
  }
  k_out<<<1, 256, 0, stream>>>(stats, esj, out, TT-1);
}

// Round 4
// 237.696 us; speedup vs baseline: 2.2705x; 2.2045x over previous
//
#include <hip/hip_runtime.h>

#define BATCH 32
#define TT 8
#define VOCAB 2048
#define EMB 256
#define NG 8192          // 4*VOCAB
#define LAT 128
#define KTOT 2304        // EMB + VOCAB
#define NKT 72           // KTOT/32 k-tiles
#define NNT 512          // NG/16 n-tiles
#define KSPLIT 8
#define KT_PER 9         // NKT/KSPLIT

typedef __bf16 bf16x8 __attribute__((ext_vector_type(8)));
typedef float  f32x4  __attribute__((ext_vector_type(4)));

// ws layout (float offsets)
#define G_OFF   0
#define G_SZ    (BATCH*NG)            // 262144 f
#define H_OFF   (G_OFF + G_SZ)
#define H_SZ    (BATCH*VOCAB)
#define C_OFF   (H_OFF + H_SZ)
#define C_SZ    (BATCH*VOCAB)
#define ST_OFF  (C_OFF + C_SZ)
#define ST_SZ   (BATCH*8*2)
#define ESJ_OFF (ST_OFF + ST_SZ)
#define ESJ_SZ  32
#define AHB_OFF (ESJ_OFF + ESJ_SZ)    // ushort region: 32*2304 ushorts
#define AHB_SZF ((BATCH*KTOT)/2)      // 36864 floats
#define BP_OFF  (AHB_OFF + AHB_SZF)   // ushort region: 512*72*64*8 ushorts (~37.7MB)

__device__ __forceinline__ float sigmoidf_(float x){ return 1.f/(1.f+__expf(-x)); }
__device__ __forceinline__ float tanhf_(float x){
  x = fminf(fmaxf(x, -10.f), 10.f);
  float e = __expf(2.f*x);
  return (e-1.f)/(e+1.f);
}
__device__ __forceinline__ unsigned short f2bf(float f){   // round-to-nearest-even
  unsigned int u = __float_as_uint(f);
  return (unsigned short)((u + 0x7FFFu + ((u>>16)&1u)) >> 16);
}

// Zero gates/h/c, write out[:,0,:]=0, init Ahb = [bf16(E[tok[:,0]]) | zeros]
__global__ __launch_bounds__(256) void k_init(
    const int* __restrict__ tok, const float* __restrict__ E,
    float* __restrict__ h, float* __restrict__ c,
    unsigned short* __restrict__ Ahb, float* __restrict__ gates,
    float* __restrict__ out){
  int i = blockIdx.x*256 + threadIdx.x;
  if (i < BATCH*NG) gates[i] = 0.f;
  if (i < BATCH*VOCAB){ h[i] = 0.f; c[i] = 0.f; }
  if (i < BATCH*KTOT){
    int b = i / KTOT, k = i % KTOT;
    Ahb[i] = (k < EMB) ? f2bf(E[(size_t)tok[b*TT+0]*EMB + k]) : (unsigned short)0;
  }
  if (i < BATCH*LAT){
    int b = i >> 7, l = i & (LAT-1);
    out[(size_t)(b*TT + 0)*LAT + l] = 0.f;     // t=0: rng=0 -> z=0 exactly
  }
}

// One-time: pack [Wi;Wh] fp32 -> bf16 in MFMA B-operand fragment order.
// Bp[nt][kt][lane][j] = W[kt*32 + (lane>>4)*8 + j][nt*16 + (lane&15)]
__global__ __launch_bounds__(256) void k_pack_w(
    const float* __restrict__ Wi, const float* __restrict__ Wh,
    unsigned short* __restrict__ Bp){
  int g = blockIdx.x*256 + threadIdx.x;          // [0, 512*72*64)
  int lane = g & 63, kt = (g>>6) % NKT, nt = g / (64*NKT);
  int n = nt*16 + (lane & 15);
  int k0 = kt*32 + (lane>>4)*8;
  unsigned int u[4];
  #pragma unroll
  for (int p=0;p<4;p++){
    int ka = k0 + 2*p, kb = k0 + 2*p + 1;
    float fa = (ka < EMB) ? Wi[(size_t)ka*NG + n] : Wh[(size_t)(ka-EMB)*NG + n];
    float fb = (kb < EMB) ? Wi[(size_t)kb*NG + n] : Wh[(size_t)(kb-EMB)*NG + n];
    u[p] = (unsigned int)f2bf(fa) | ((unsigned int)f2bf(fb) << 16);
  }
  *(uint4*)&Bp[(size_t)g*8] = make_uint4(u[0],u[1],u[2],u[3]);
}

// gates += [x|h](bf16) @ [Wi;Wh](bf16 packed).  No LDS tile, no staging barrier.
// Wave: M=32 x N=32 tile, K = 288 (9 k-tiles); KSPLIT=8 k-slices via atomics.
// Designated block (0,0) also finalizes the PREVIOUS step's output (t>=2).
__global__ __launch_bounds__(256) void k_gemm(
    const unsigned short* __restrict__ Ahb, const unsigned short* __restrict__ Bp,
    float* __restrict__ gates, const float* __restrict__ stats,
    const float* __restrict__ esj, float* __restrict__ out, int t){
  const int tid = threadIdx.x;

  if (blockIdx.x==0 && blockIdx.y==0 && t>=2){    // block-uniform branch
    __shared__ float vsh[BATCH];
    if (tid < BATCH){
      float Z=0.f, S=0.f;
      #pragma unroll
      for (int jc=0;jc<8;jc++){ Z += stats[(tid*8+jc)*2]; S += stats[(tid*8+jc)*2+1]; }
      vsh[tid] = (3.f*S + 1.5f*esj[tid])/Z;
    }
    __syncthreads();
    for (int i=tid; i<BATCH*LAT; i+=256)
      out[(size_t)((i>>7)*TT + (t-1))*LAT + (i&(LAT-1))] = vsh[i>>7];
  }

  const int w = tid >> 6, lane = tid & 63;
  const int quad = lane >> 4, col = lane & 15;
  const int nt0 = blockIdx.x*8 + w*2;            // blockIdx.x in [0,64)
  const int kt0 = blockIdx.y*KT_PER;
  const bf16x8* __restrict__ AhV = (const bf16x8*)Ahb;  // idx m*288 + kt*4 + quad
  const bf16x8* __restrict__ BpV = (const bf16x8*)Bp;   // idx (nt*NKT+kt)*64 + lane

  f32x4 acc00={0,0,0,0}, acc01={0,0,0,0}, acc10={0,0,0,0}, acc11={0,0,0,0};
  const int a0b = col*(KTOT/8), a1b = (16+col)*(KTOT/8);
  #pragma unroll 3
  for (int kt = kt0; kt < kt0+KT_PER; kt++){
    bf16x8 b0 = BpV[(nt0*NKT + kt)*64 + lane];
    bf16x8 b1 = BpV[((nt0+1)*NKT + kt)*64 + lane];
    bf16x8 a0 = AhV[a0b + kt*4 + quad];
    bf16x8 a1 = AhV[a1b + kt*4 + quad];
    acc00 = __builtin_amdgcn_mfma_f32_16x16x32_bf16(a0,b0,acc00,0,0,0);
    acc01 = __builtin_amdgcn_mfma_f32_16x16x32_bf16(a0,b1,acc01,0,0,0);
    acc10 = __builtin_amdgcn_mfma_f32_16x16x32_bf16(a1,b0,acc10,0,0,0);
    acc11 = __builtin_amdgcn_mfma_f32_16x16x32_bf16(a1,b1,acc11,0,0,0);
  }
  const int rowd = quad*4;
  #pragma unroll
  for (int r=0;r<4;r++){
    atomicAdd(&gates[(size_t)(rowd+r)*NG + nt0*16 + col],        acc00[r]);
    atomicAdd(&gates[(size_t)(rowd+r)*NG + (nt0+1)*16 + col],    acc01[r]);
    atomicAdd(&gates[(size_t)(16+rowd+r)*NG + nt0*16 + col],     acc10[r]);
    atomicAdd(&gates[(size_t)(16+rowd+r)*NG + (nt0+1)*16 + col], acc11[r]);
  }
}

// gates -> LSTM cell (masked) -> h,c ; re-zero gates for next step; write bf16 h
// into Ahb; jc==0 blocks stage next step's x-row; partial softmax stats.
__global__ __launch_bounds__(256) void k_cellred(
    const int* __restrict__ tok, const float* __restrict__ E,
    const float* __restrict__ bias, float* __restrict__ gates,
    float* __restrict__ h, float* __restrict__ c, unsigned short* __restrict__ Ahb,
    float* __restrict__ stats, float* __restrict__ esj, int t){
  const int tid = threadIdx.x;
  const int jc = blockIdx.x, b = blockIdx.y;
  const int j = jc*256 + tid;
  const int lane = tid & 63, wid = tid >> 6;

  float* gp = gates + (size_t)b*NG;
  float ip = bias[j]          + gp[j];
  float fp = bias[j+VOCAB]    + gp[j+VOCAB];
  float gg = bias[j+2*VOCAB]  + gp[j+2*VOCAB];
  float op = bias[j+3*VOCAB]  + gp[j+3*VOCAB];
  gp[j] = 0.f; gp[j+VOCAB] = 0.f; gp[j+2*VOCAB] = 0.f; gp[j+3*VOCAB] = 0.f;

  float cold = c[b*VOCAB + j];
  float cn = sigmoidf_(fp)*cold + sigmoidf_(ip)*tanhf_(gg);
  float hn = sigmoidf_(op)*tanhf_(cn);
  const bool upd = tok[b*TT + (t-1)] != 0;
  float hf = upd ? hn : h[b*VOCAB + j];
  float cf = upd ? cn : cold;
  h[b*VOCAB + j] = hf;
  c[b*VOCAB + j] = cf;
  Ahb[b*KTOT + EMB + j] = f2bf(hf);
  if (jc == 0 && t < TT-1)   // stage next step's x-row: x = E[tok[:,t]]
    Ahb[b*KTOT + tid] = f2bf(E[(size_t)tok[b*TT + t]*EMB + tid]);

  const int sj = tok[b*TT + t];
  float e = __expf(hf);                 // h in (-1,1): no max-pass needed
  float z = e, s = (j < sj) ? e : 0.f;
  if (j == sj) esj[b] = e;

  __shared__ float zsh[4], ssh[4];
  #pragma unroll
  for (int off=32; off; off>>=1){ z += __shfl_down(z, off); s += __shfl_down(s, off); }
  if (lane==0){ zsh[wid] = z; ssh[wid] = s; }
  __syncthreads();
  if (tid==0){
    stats[(b*8 + jc)*2 + 0] = zsh[0]+zsh[1]+zsh[2]+zsh[3];
    stats[(b*8 + jc)*2 + 1] = ssh[0]+ssh[1]+ssh[2]+ssh[3];
  }
}

// z[b,t,:] = (3*S + 1.5*e_sj)/Z  broadcast over LAT
__global__ __launch_bounds__(256) void k_out(
    const float* __restrict__ stats, const float* __restrict__ esj,
    float* __restrict__ out, int t){
  const int tid = threadIdx.x;
  __shared__ float vsh[BATCH];
  if (tid < BATCH){
    float Z=0.f, S=0.f;
    #pragma unroll
    for (int jc=0;jc<8;jc++){ Z += stats[(tid*8+jc)*2]; S += stats[(tid*8+jc)*2+1]; }
    vsh[tid] = (3.f*S + 1.5f*esj[tid])/Z;
  }
  __syncthreads();
  for (int i=tid; i<BATCH*LAT; i+=256)
    out[(size_t)((i>>7)*TT + t)*LAT + (i&(LAT-1))] = vsh[i>>7];
}

extern "C" void kernel_launch(void* const* d_in, const int* in_sizes, int n_in,
                              void* d_out, int out_size, void* d_ws, size_t ws_size,
                              hipStream_t stream){
  const int*   tok  = (const int*)d_in[0];
  const float* E    = (const float*)d_in[1];
  const float* Wi   = (const float*)d_in[2];
  const float* Wh   = (const float*)d_in[3];
  const float* bias = (const float*)d_in[4];
  float* out = (float*)d_out;
  float* ws  = (float*)d_ws;
  float* gates = ws + G_OFF;
  float* h     = ws + H_OFF;
  float* c     = ws + C_OFF;
  float* stats = ws + ST_OFF;
  float* esj   = ws + ESJ_OFF;
  unsigned short* Ahb = (unsigned short*)(ws + AHB_OFF);
  unsigned short* Bp  = (unsigned short*)(ws + BP_OFF);

  k_init<<<1024, 256, 0, stream>>>(tok, E, h, c, Ahb, gates, out);
  k_pack_w<<<(NNT*NKT*64)/256, 256, 0, stream>>>(Wi, Wh, Bp);
  for (int t = 1; t < TT; t++){
    k_gemm<<<dim3(64, KSPLIT), 256, 0, stream>>>(Ahb, Bp, gates, stats, esj, out, t);
    k_cellred<<<dim3(8, BATCH), 256, 0, stream>>>(tok, E, bias, gates, h, c, Ahb, stats, esj, t);
  }
  k_out<<<1, 256, 0, stream>>>(stats, esj, out, TT-1);
}